// Round 3
// baseline (1621.002 us; speedup 1.0000x reference)
//
#include <hip/hip_runtime.h>

// Problem constants (B, SQ, SKV, E, H, D) = (4, 2048, 2048, 2048, 16, 128)
#define B_   4
#define SQ_  2048
#define SKV_ 2048
#define E_   2048
#define H_   16
#define D_   128
#define EE_  (E_*E_)        // 4194304
#define BSE_ (B_*SQ_*E_)    // 16777216

typedef unsigned short u16;
typedef unsigned int   u32;
typedef __attribute__((ext_vector_type(4))) float f32x4;
typedef __attribute__((ext_vector_type(8))) short bf16x8;

__device__ __forceinline__ u16 f2bf(float f) {
  union { float f; u32 u; } x; x.f = f;
  u32 r = x.u + 0x7FFFu + ((x.u >> 16) & 1u);   // round-to-nearest-even
  return (u16)(r >> 16);
}
__device__ __forceinline__ float bf2f(u16 h) {
  union { u32 u; float f; } x; x.u = ((u32)h) << 16; return x.f;
}
__device__ __forceinline__ u32 pack2(float a, float b) {
  return (u32)f2bf(a) | ((u32)f2bf(b) << 16);
}
__device__ __forceinline__ void gload_lds16(const void* g, void* l) {
  __builtin_amdgcn_global_load_lds(
      (const __attribute__((address_space(1))) u32*)g,
      (__attribute__((address_space(3))) u32*)l, 16, 0, 0);
}

// ---------------- f32 -> bf16 cast (8 elems/thread) ----------------
__global__ __launch_bounds__(256)
void cast_kernel(const float* __restrict__ in, u16* __restrict__ out, int n8) {
  int i = blockIdx.x * 256 + threadIdx.x;
  if (i >= n8) return;
  const float4* p = (const float4*)(in + (size_t)i * 8);
  float4 a = p[0], b = p[1];
  uint4 o;
  o.x = pack2(a.x, a.y); o.y = pack2(a.z, a.w);
  o.z = pack2(b.x, b.y); o.w = pack2(b.z, b.w);
  *(uint4*)(out + (size_t)i * 8) = o;
}

// ---------------- m97-style bf16 GEMM: C = (A @ Bt^T + bias) * alpha ----------
// A: MxK row-major bf16.  Bt: NxK row-major bf16 (i.e. torch Linear weight).
// OMODE 0: bf16 out [M][N].  OMODE 1: bf16 out transposed per-batch
//   (Vt[b][n][s], flat = b*N*SKV + n*SKV + s, m = b*SKV + s).  OMODE 2: f32 out [M][N].
template<int OMODE>
__global__ __launch_bounds__(256)
void gemm_bt(const u16* __restrict__ A, const u16* __restrict__ Bt,
             const float* __restrict__ bias, void* __restrict__ Cout,
             int M, int N, int K, float alpha)
{
  __shared__ __align__(16) u16 As[128 * 32];
  __shared__ __align__(16) u16 Bs[128 * 32];
  const int tid  = threadIdx.x;
  const int lane = tid & 63;
  const int l15  = lane & 15, lg = lane >> 4;
  const int w = tid >> 6, wr = w >> 1, wc = w & 1;
  const int m0 = blockIdx.y * 128, n0 = blockIdx.x * 128;

  // Staging: 512 chunks of 16B per tile (rows 0..127 x 4 kchunks), chunk c at LDS byte c*16.
  const int c0 = tid, c1 = tid + 256;
  const u16* ga0 = A  + (size_t)(m0 + (c0 >> 2)) * K + (c0 & 3) * 8;
  const u16* ga1 = A  + (size_t)(m0 + (c1 >> 2)) * K + (c1 & 3) * 8;
  const u16* gb0 = Bt + (size_t)(n0 + (c0 >> 2)) * K + (c0 & 3) * 8;
  const u16* gb1 = Bt + (size_t)(n0 + (c1 >> 2)) * K + (c1 & 3) * 8;
  u16* la0 = &As[c0 * 8]; u16* la1 = &As[c1 * 8];
  u16* lb0 = &Bs[c0 * 8]; u16* lb1 = &Bs[c1 * 8];

  f32x4 acc[4][4];
#pragma unroll
  for (int i = 0; i < 4; i++)
#pragma unroll
    for (int j = 0; j < 4; j++) acc[i][j] = (f32x4){0.f, 0.f, 0.f, 0.f};

  const u16* pa = &As[(wr * 64 + l15) * 32 + lg * 8];
  const u16* pb = &Bs[(wc * 64 + l15) * 32 + lg * 8];

  for (int kt = 0; kt < K; kt += 32) {
    gload_lds16(ga0 + kt, la0);
    gload_lds16(ga1 + kt, la1);
    gload_lds16(gb0 + kt, lb0);
    gload_lds16(gb1 + kt, lb1);
    __syncthreads();
    bf16x8 af[4], bfr[4];
#pragma unroll
    for (int i = 0; i < 4; i++) {
      af[i]  = *(const bf16x8*)(pa + i * 16 * 32);
      bfr[i] = *(const bf16x8*)(pb + i * 16 * 32);
    }
#pragma unroll
    for (int mi = 0; mi < 4; mi++)
#pragma unroll
      for (int ni = 0; ni < 4; ni++)
        acc[mi][ni] = __builtin_amdgcn_mfma_f32_16x16x32_bf16(af[mi], bfr[ni], acc[mi][ni], 0, 0, 0);
    __syncthreads();
  }

  // Epilogue. C/D layout: col = lane&15, row = (lane>>4)*4 + reg.
#pragma unroll
  for (int ni = 0; ni < 4; ni++) {
    const int n = n0 + wc * 64 + ni * 16 + l15;
    const float bs = bias[n];
#pragma unroll
    for (int mi = 0; mi < 4; mi++) {
      const int mbase = m0 + wr * 64 + mi * 16 + lg * 4;
      f32x4 v = acc[mi][ni];
      if constexpr (OMODE == 2) {
        float* C = (float*)Cout;
#pragma unroll
        for (int r = 0; r < 4; r++) C[(size_t)(mbase + r) * N + n] = (v[r] + bs) * alpha;
      } else if constexpr (OMODE == 0) {
        u16* C = (u16*)Cout;
#pragma unroll
        for (int r = 0; r < 4; r++) C[(size_t)(mbase + r) * N + n] = f2bf((v[r] + bs) * alpha);
      } else {
        u16* C = (u16*)Cout;
        const int b = mbase / SKV_, s = mbase & (SKV_ - 1);  // 4 rows stay in one b
        ushort4 o;
        o.x = f2bf((v[0] + bs) * alpha); o.y = f2bf((v[1] + bs) * alpha);
        o.z = f2bf((v[2] + bs) * alpha); o.w = f2bf((v[3] + bs) * alpha);
        *(ushort4*)((u16*)C + (size_t)b * N * SKV_ + (size_t)n * SKV_ + s) = o;
      }
    }
  }
}

// ---------------- flash attention ----------------
// Qp: [B,SQ,E] bf16 (pre-scaled by 1/sqrt(D)), Kp: [B,SKV,E] bf16,
// Vt: [B][E][SKV] bf16 (per-head transposed), O: [B,SQ,E] bf16.
// Block = 4 waves x 16 q-rows; KV tile = 32.
__global__ __launch_bounds__(256)
void attn_fwd(const u16* __restrict__ Qp, const u16* __restrict__ Kp,
              const u16* __restrict__ Vt, u16* __restrict__ O)
{
  __shared__ __align__(16) u16 Plds[4][16 * 32];
  const int lane = threadIdx.x & 63;
  const int w    = threadIdx.x >> 6;
  const int l15  = lane & 15, lg = lane >> 4;
  const int bh = blockIdx.y, b = bh >> 4, h = bh & 15;
  const int q0 = blockIdx.x * 64 + w * 16;

  // Q fragments: 4 x (16 rows x 32 d)
  bf16x8 qf[4];
  {
    const u16* qp = Qp + (size_t)(b * SQ_ + q0 + l15) * E_ + h * D_ + lg * 8;
#pragma unroll
    for (int kk = 0; kk < 4; kk++) qf[kk] = *(const bf16x8*)(qp + kk * 32);
  }

  f32x4 o[8];
#pragma unroll
  for (int i = 0; i < 8; i++) o[i] = (f32x4){0.f, 0.f, 0.f, 0.f};
  float mrow[4] = {-1e30f, -1e30f, -1e30f, -1e30f};
  float lrow[4] = {0.f, 0.f, 0.f, 0.f};

  const u16* kbase = Kp + (size_t)b * SKV_ * E_ + h * D_ + lg * 8;
  const u16* vbase = Vt + (size_t)b * E_ * SKV_ + (size_t)(h * D_ + l15) * SKV_ + lg * 8;

  for (int kv0 = 0; kv0 < SKV_; kv0 += 32) {
    // S tile 16x32 = two 16x16 C-frags
    f32x4 s0 = (f32x4){0.f,0.f,0.f,0.f}, s1 = (f32x4){0.f,0.f,0.f,0.f};
#pragma unroll
    for (int kk = 0; kk < 4; kk++) {
      bf16x8 k0 = *(const bf16x8*)(kbase + (size_t)(kv0 + l15) * E_ + kk * 32);
      bf16x8 k1 = *(const bf16x8*)(kbase + (size_t)(kv0 + 16 + l15) * E_ + kk * 32);
      s0 = __builtin_amdgcn_mfma_f32_16x16x32_bf16(qf[kk], k0, s0, 0, 0, 0);
      s1 = __builtin_amdgcn_mfma_f32_16x16x32_bf16(qf[kk], k1, s1, 0, 0, 0);
    }
    // online softmax per q-row (row = lg*4 + r, 16 kv entries per frag across lanes l15)
    float fac[4], p0[4], p1[4];
#pragma unroll
    for (int r = 0; r < 4; r++) {
      float mx = fmaxf(s0[r], s1[r]);
      mx = fmaxf(mx, __shfl_xor(mx, 1));
      mx = fmaxf(mx, __shfl_xor(mx, 2));
      mx = fmaxf(mx, __shfl_xor(mx, 4));
      mx = fmaxf(mx, __shfl_xor(mx, 8));
      const float mnew = fmaxf(mrow[r], mx);
      fac[r] = __expf(mrow[r] - mnew);
      p0[r] = __expf(s0[r] - mnew);
      p1[r] = __expf(s1[r] - mnew);
      float ps = p0[r] + p1[r];
      ps += __shfl_xor(ps, 1);
      ps += __shfl_xor(ps, 2);
      ps += __shfl_xor(ps, 4);
      ps += __shfl_xor(ps, 8);
      lrow[r] = lrow[r] * fac[r] + ps;
      mrow[r] = mnew;
    }
#pragma unroll
    for (int nf = 0; nf < 8; nf++)
#pragma unroll
      for (int r = 0; r < 4; r++) o[nf][r] *= fac[r];
    // P -> LDS (per-wave private; same-wave RAW handled by compiler lgkmcnt)
#pragma unroll
    for (int r = 0; r < 4; r++) {
      Plds[w][(lg * 4 + r) * 32 + l15]      = f2bf(p0[r]);
      Plds[w][(lg * 4 + r) * 32 + 16 + l15] = f2bf(p1[r]);
    }
    bf16x8 pf = *(const bf16x8*)&Plds[w][l15 * 32 + lg * 8];
#pragma unroll
    for (int nf = 0; nf < 8; nf++) {
      bf16x8 vf = *(const bf16x8*)(vbase + (size_t)nf * 16 * SKV_ + kv0);
      o[nf] = __builtin_amdgcn_mfma_f32_16x16x32_bf16(pf, vf, o[nf], 0, 0, 0);
    }
  }

  // epilogue: divide by row sum, write bf16 [B,SQ,E]
  u16* ob = O + (size_t)(b * SQ_ + q0 + lg * 4) * E_ + h * D_ + l15;
#pragma unroll
  for (int r = 0; r < 4; r++) {
    const float inv = 1.f / lrow[r];
#pragma unroll
    for (int nf = 0; nf < 8; nf++)
      ob[(size_t)r * E_ + nf * 16] = f2bf(o[nf][r] * inv);
  }
}

// ---------------- LayerNorm over E=2048, bf16 in -> bf16 out ----------------
__global__ __launch_bounds__(256)
void ln_kernel(const u16* __restrict__ X, const float* __restrict__ gam,
               const float* __restrict__ bet, u16* __restrict__ Y)
{
  __shared__ float red[8];
  const int row = blockIdx.x, t = threadIdx.x;
  const u16* x = X + (size_t)row * E_ + t * 8;
  uint4 raw = *(const uint4*)x;
  float v[8];
  v[0] = bf2f((u16)(raw.x & 0xffff)); v[1] = bf2f((u16)(raw.x >> 16));
  v[2] = bf2f((u16)(raw.y & 0xffff)); v[3] = bf2f((u16)(raw.y >> 16));
  v[4] = bf2f((u16)(raw.z & 0xffff)); v[5] = bf2f((u16)(raw.z >> 16));
  v[6] = bf2f((u16)(raw.w & 0xffff)); v[7] = bf2f((u16)(raw.w >> 16));
  float s = 0.f, ss = 0.f;
#pragma unroll
  for (int i = 0; i < 8; i++) { s += v[i]; ss += v[i] * v[i]; }
#pragma unroll
  for (int off = 1; off < 64; off <<= 1) { s += __shfl_xor(s, off); ss += __shfl_xor(ss, off); }
  const int wv = t >> 6, lane = t & 63;
  if (lane == 0) { red[wv] = s; red[4 + wv] = ss; }
  __syncthreads();
  s  = red[0] + red[1] + red[2] + red[3];
  ss = red[4] + red[5] + red[6] + red[7];
  const float mean = s * (1.f / E_);
  const float var  = ss * (1.f / E_) - mean * mean;
  const float rstd = rsqrtf(var + 1e-5f);
  const float4* gp = (const float4*)(gam + t * 8);
  const float4* bp = (const float4*)(bet + t * 8);
  float4 g0 = gp[0], g1 = gp[1], b0 = bp[0], b1 = bp[1];
  float y[8];
  y[0] = (v[0] - mean) * rstd * g0.x + b0.x;
  y[1] = (v[1] - mean) * rstd * g0.y + b0.y;
  y[2] = (v[2] - mean) * rstd * g0.z + b0.z;
  y[3] = (v[3] - mean) * rstd * g0.w + b0.w;
  y[4] = (v[4] - mean) * rstd * g1.x + b1.x;
  y[5] = (v[5] - mean) * rstd * g1.y + b1.y;
  y[6] = (v[6] - mean) * rstd * g1.z + b1.z;
  y[7] = (v[7] - mean) * rstd * g1.w + b1.w;
  uint4 o;
  o.x = pack2(y[0], y[1]); o.y = pack2(y[2], y[3]);
  o.z = pack2(y[4], y[5]); o.w = pack2(y[6], y[7]);
  *(uint4*)(Y + (size_t)row * E_ + t * 8) = o;
}

extern "C" void kernel_launch(void* const* d_in, const int* in_sizes, int n_in,
                              void* d_out, int out_size, void* d_ws, size_t ws_size,
                              hipStream_t stream) {
  const float* query = (const float*)d_in[0];
  const float* key_  = (const float*)d_in[1];
  const float* value = (const float*)d_in[2];
  const float* Wq = (const float*)d_in[3];
  const float* bq = (const float*)d_in[4];
  const float* Wk = (const float*)d_in[5];
  const float* bk = (const float*)d_in[6];
  const float* Wv = (const float*)d_in[7];
  const float* bv = (const float*)d_in[8];
  const float* ln_g = (const float*)d_in[9];
  const float* ln_b = (const float*)d_in[10];
  const float* Wo = (const float*)d_in[11];
  const float* bo = (const float*)d_in[12];
  float* out = (float*)d_out;

  char* ws = (char*)d_ws;
  u16* wqb = (u16*)(ws + 0);            // 8 MB each
  u16* wkb = (u16*)(ws + 8388608);
  u16* wvb = (u16*)(ws + 16777216);
  u16* wob = (u16*)(ws + 25165824);
  u16* xb  = (u16*)(ws + 33554432);     // 32 MB, reused: cast buf -> attn out
  u16* qp  = (u16*)(ws + 67108864);     // 32 MB, reused: Q proj -> LN out
  u16* kp  = (u16*)(ws + 100663296);    // 32 MB
  u16* vt  = (u16*)(ws + 134217728);    // 32 MB  (total 160 MB)
  u16* attn  = xb;
  u16* lnout = qp;

  const dim3 blk(256);
  const dim3 ggrid(E_ / 128, (B_ * SQ_) / 128);  // (16, 64)
  const float qscale = 0.08838834764831845f;      // 1/sqrt(128)

  // weight casts
  cast_kernel<<<EE_ / 8 / 256, blk, 0, stream>>>(Wq, wqb, EE_ / 8);
  cast_kernel<<<EE_ / 8 / 256, blk, 0, stream>>>(Wk, wkb, EE_ / 8);
  cast_kernel<<<EE_ / 8 / 256, blk, 0, stream>>>(Wv, wvb, EE_ / 8);
  cast_kernel<<<EE_ / 8 / 256, blk, 0, stream>>>(Wo, wob, EE_ / 8);

  // Q = (query @ Wq^T + bq) * 1/sqrt(D)
  cast_kernel<<<BSE_ / 8 / 256, blk, 0, stream>>>(query, xb, BSE_ / 8);
  gemm_bt<0><<<ggrid, blk, 0, stream>>>(xb, wqb, bq, qp, B_ * SQ_, E_, E_, qscale);
  // K
  cast_kernel<<<BSE_ / 8 / 256, blk, 0, stream>>>(key_, xb, BSE_ / 8);
  gemm_bt<0><<<ggrid, blk, 0, stream>>>(xb, wkb, bk, kp, B_ * SQ_, E_, E_, 1.0f);
  // V (transposed per-head write)
  cast_kernel<<<BSE_ / 8 / 256, blk, 0, stream>>>(value, xb, BSE_ / 8);
  gemm_bt<1><<<ggrid, blk, 0, stream>>>(xb, wvb, bv, vt, B_ * SQ_, E_, E_, 1.0f);

  // attention
  attn_fwd<<<dim3(SQ_ / 64, B_ * H_), blk, 0, stream>>>(qp, kp, vt, attn);

  // layernorm
  ln_kernel<<<B_ * SQ_, blk, 0, stream>>>(attn, ln_g, ln_b, lnout);

  // out = lnout @ Wo^T + bo  (f32 out)
  gemm_bt<2><<<ggrid, blk, 0, stream>>>(lnout, wob, bo, out, B_ * SQ_, E_, E_, 1.0f);
}

// Round 4
// 1619.583 us; speedup vs baseline: 1.0009x; 1.0009x over previous
//
#include <hip/hip_runtime.h>

// Problem constants (B, SQ, SKV, E, H, D) = (4, 2048, 2048, 2048, 16, 128)
#define B_   4
#define SQ_  2048
#define SKV_ 2048
#define E_   2048
#define H_   16
#define D_   128
#define EE_  (E_*E_)        // 4194304
#define BSE_ (B_*SQ_*E_)    // 16777216

typedef unsigned short u16;
typedef unsigned int   u32;
typedef __attribute__((ext_vector_type(4))) float f32x4;
typedef __attribute__((ext_vector_type(8))) short bf16x8;

__device__ __forceinline__ u16 f2bf(float f) {
  union { float f; u32 u; } x; x.f = f;
  u32 r = x.u + 0x7FFFu + ((x.u >> 16) & 1u);   // round-to-nearest-even
  return (u16)(r >> 16);
}
__device__ __forceinline__ float bf2f(u16 h) {
  union { u32 u; float f; } x; x.u = ((u32)h) << 16; return x.f;
}
__device__ __forceinline__ u32 pack2(float a, float b) {
  return (u32)f2bf(a) | ((u32)f2bf(b) << 16);
}
__device__ __forceinline__ void gload_lds16(const void* g, void* l) {
  __builtin_amdgcn_global_load_lds(
      (const __attribute__((address_space(1))) u32*)g,
      (__attribute__((address_space(3))) u32*)l, 16, 0, 0);
}

// ---------------- f32 -> bf16 cast (8 elems/thread) ----------------
__global__ __launch_bounds__(256)
void cast_kernel(const float* __restrict__ in, u16* __restrict__ out, int n8) {
  int i = blockIdx.x * 256 + threadIdx.x;
  if (i >= n8) return;
  const float4* p = (const float4*)(in + (size_t)i * 8);
  float4 a = p[0], b = p[1];
  uint4 o;
  o.x = pack2(a.x, a.y); o.y = pack2(a.z, a.w);
  o.z = pack2(b.x, b.y); o.w = pack2(b.z, b.w);
  *(uint4*)(out + (size_t)i * 8) = o;
}

// ---------------- m97-style bf16 GEMM: C = (A @ Bt^T + bias) * alpha ----------
// A: MxK row-major bf16.  Bt: NxK row-major bf16 (i.e. torch Linear weight).
// OMODE 0: bf16 out [M][N].  OMODE 1: bf16 out transposed per-batch
//   (Vt[b][n][s]).  OMODE 2: f32 out [M][N].
template<int OMODE>
__global__ __launch_bounds__(256)
void gemm_bt(const u16* __restrict__ A, const u16* __restrict__ Bt,
             const float* __restrict__ bias, void* __restrict__ Cout,
             int M, int N, int K, float alpha)
{
  __shared__ __align__(16) u16 As[128 * 32];
  __shared__ __align__(16) u16 Bs[128 * 32];
  const int tid  = threadIdx.x;
  const int lane = tid & 63;
  const int l15  = lane & 15, lg = lane >> 4;
  const int w = tid >> 6, wr = w >> 1, wc = w & 1;
  const int m0 = blockIdx.y * 128, n0 = blockIdx.x * 128;

  const int c0 = tid, c1 = tid + 256;
  const u16* ga0 = A  + (size_t)(m0 + (c0 >> 2)) * K + (c0 & 3) * 8;
  const u16* ga1 = A  + (size_t)(m0 + (c1 >> 2)) * K + (c1 & 3) * 8;
  const u16* gb0 = Bt + (size_t)(n0 + (c0 >> 2)) * K + (c0 & 3) * 8;
  const u16* gb1 = Bt + (size_t)(n0 + (c1 >> 2)) * K + (c1 & 3) * 8;
  u16* la0 = &As[c0 * 8]; u16* la1 = &As[c1 * 8];
  u16* lb0 = &Bs[c0 * 8]; u16* lb1 = &Bs[c1 * 8];

  f32x4 acc[4][4];
#pragma unroll
  for (int i = 0; i < 4; i++)
#pragma unroll
    for (int j = 0; j < 4; j++) acc[i][j] = (f32x4){0.f, 0.f, 0.f, 0.f};

  const u16* pa = &As[(wr * 64 + l15) * 32 + lg * 8];
  const u16* pb = &Bs[(wc * 64 + l15) * 32 + lg * 8];

  for (int kt = 0; kt < K; kt += 32) {
    gload_lds16(ga0 + kt, la0);
    gload_lds16(ga1 + kt, la1);
    gload_lds16(gb0 + kt, lb0);
    gload_lds16(gb1 + kt, lb1);
    __syncthreads();
    bf16x8 af[4], bfr[4];
#pragma unroll
    for (int i = 0; i < 4; i++) {
      af[i]  = *(const bf16x8*)(pa + i * 16 * 32);
      bfr[i] = *(const bf16x8*)(pb + i * 16 * 32);
    }
#pragma unroll
    for (int mi = 0; mi < 4; mi++)
#pragma unroll
      for (int ni = 0; ni < 4; ni++)
        acc[mi][ni] = __builtin_amdgcn_mfma_f32_16x16x32_bf16(af[mi], bfr[ni], acc[mi][ni], 0, 0, 0);
    __syncthreads();
  }

  // Epilogue. C/D layout: col = lane&15, row = (lane>>4)*4 + reg.
#pragma unroll
  for (int ni = 0; ni < 4; ni++) {
    const int n = n0 + wc * 64 + ni * 16 + l15;
    const float bs = bias[n];
#pragma unroll
    for (int mi = 0; mi < 4; mi++) {
      const int mbase = m0 + wr * 64 + mi * 16 + lg * 4;
      f32x4 v = acc[mi][ni];
      if constexpr (OMODE == 2) {
        float* C = (float*)Cout;
#pragma unroll
        for (int r = 0; r < 4; r++) C[(size_t)(mbase + r) * N + n] = (v[r] + bs) * alpha;
      } else if constexpr (OMODE == 0) {
        u16* C = (u16*)Cout;
#pragma unroll
        for (int r = 0; r < 4; r++) C[(size_t)(mbase + r) * N + n] = f2bf((v[r] + bs) * alpha);
      } else {
        u16* C = (u16*)Cout;
        const int b = mbase / SKV_, s = mbase & (SKV_ - 1);  // 4 rows stay in one b
        ushort4 o;
        o.x = f2bf((v[0] + bs) * alpha); o.y = f2bf((v[1] + bs) * alpha);
        o.z = f2bf((v[2] + bs) * alpha); o.w = f2bf((v[3] + bs) * alpha);
        *(ushort4*)((u16*)C + (size_t)b * N * SKV_ + (size_t)n * SKV_ + s) = o;
      }
    }
  }
}

// ---------------- flash attention ----------------
// Qp: [B,SQ,E] bf16 (pre-scaled by 1/sqrt(D)), Kp: [B,SKV,E] bf16,
// Vt: [B][E][SKV] bf16 (per-head transposed), O: [B,SQ,E] bf16.
// Block = 4 waves x 16 q-rows; KV tile = 32.
// Round-3 changes: defer-max (THR=8, skip cross-lane max + rescale when
// __all(localmax <= m+8)), per-lane partial row-sums (single epilogue
// reduce), K next-tile + V current-tile register prefetch issued before
// softmax, P-LDS padded to stride 40 (80B, 16B-aligned b128 reads),
// s_setprio(1) around MFMA clusters.
__global__ __launch_bounds__(256)
void attn_fwd(const u16* __restrict__ Qp, const u16* __restrict__ Kp,
              const u16* __restrict__ Vt, u16* __restrict__ O)
{
  __shared__ __align__(16) u16 Plds[4][16 * 40];
  const int lane = threadIdx.x & 63;
  const int w    = threadIdx.x >> 6;
  const int l15  = lane & 15, lg = lane >> 4;
  const int bh = blockIdx.y, b = bh >> 4, h = bh & 15;
  const int q0 = blockIdx.x * 64 + w * 16;

  // Q fragments: 4 x (16 rows x 32 d)
  bf16x8 qf[4];
  {
    const u16* qp = Qp + (size_t)(b * SQ_ + q0 + l15) * E_ + h * D_ + lg * 8;
#pragma unroll
    for (int kk = 0; kk < 4; kk++) qf[kk] = *(const bf16x8*)(qp + kk * 32);
  }

  f32x4 o[8];
#pragma unroll
  for (int i = 0; i < 8; i++) o[i] = (f32x4){0.f, 0.f, 0.f, 0.f};
  float mrow[4] = {-3e38f, -3e38f, -3e38f, -3e38f};   // wave-uniform per row
  float lsum[4] = {0.f, 0.f, 0.f, 0.f};               // per-lane partials

  const u16* kbase = Kp + (size_t)b * SKV_ * E_ + h * D_ + lg * 8;
  const u16* vbase = Vt + (size_t)b * E_ * SKV_ + (size_t)(h * D_ + l15) * SKV_ + lg * 8;

  // preload K tile 0: kf[kk] = rows kv0+l15, kf[4+kk] = rows kv0+16+l15
  bf16x8 kf[8], vf[8];
#pragma unroll
  for (int kk = 0; kk < 4; kk++) {
    kf[kk]     = *(const bf16x8*)(kbase + (size_t)(l15) * E_ + kk * 32);
    kf[4 + kk] = *(const bf16x8*)(kbase + (size_t)(16 + l15) * E_ + kk * 32);
  }

  for (int t = 0; t < SKV_ / 32; ++t) {
    const int kv0 = t * 32;
    // ---- QK^T: S tile 16x32 = two 16x16 C-frags ----
    f32x4 s0 = (f32x4){0.f,0.f,0.f,0.f}, s1 = (f32x4){0.f,0.f,0.f,0.f};
    __builtin_amdgcn_s_setprio(1);
#pragma unroll
    for (int kk = 0; kk < 4; kk++) {
      s0 = __builtin_amdgcn_mfma_f32_16x16x32_bf16(qf[kk], kf[kk],     s0, 0, 0, 0);
      s1 = __builtin_amdgcn_mfma_f32_16x16x32_bf16(qf[kk], kf[4 + kk], s1, 0, 0, 0);
    }
    __builtin_amdgcn_s_setprio(0);
    // ---- prefetch: next K tile + this tile's V (hide latency under softmax)
    const int kvn = (t < SKV_ / 32 - 1) ? kv0 + 32 : 0;
#pragma unroll
    for (int kk = 0; kk < 4; kk++) {
      kf[kk]     = *(const bf16x8*)(kbase + (size_t)(kvn + l15) * E_ + kk * 32);
      kf[4 + kk] = *(const bf16x8*)(kbase + (size_t)(kvn + 16 + l15) * E_ + kk * 32);
    }
#pragma unroll
    for (int nf = 0; nf < 8; nf++)
      vf[nf] = *(const bf16x8*)(vbase + (size_t)nf * 16 * SKV_ + kv0);

    // ---- online softmax, defer-max ----
    float lmax[4];
#pragma unroll
    for (int r = 0; r < 4; r++) lmax[r] = fmaxf(s0[r], s1[r]);
    int c = (lmax[0] <= mrow[0] + 8.f) & (lmax[1] <= mrow[1] + 8.f) &
            (lmax[2] <= mrow[2] + 8.f) & (lmax[3] <= mrow[3] + 8.f);
    if (!__all(c)) {
      // full cross-lane max + rescale (rare)
#pragma unroll
      for (int r = 0; r < 4; r++) {
        float mx = lmax[r];
        mx = fmaxf(mx, __shfl_xor(mx, 1));
        mx = fmaxf(mx, __shfl_xor(mx, 2));
        mx = fmaxf(mx, __shfl_xor(mx, 4));
        mx = fmaxf(mx, __shfl_xor(mx, 8));
        const float mnew = fmaxf(mrow[r], mx);
        const float fac = __expf(mrow[r] - mnew);
        lsum[r] *= fac;
#pragma unroll
        for (int nf = 0; nf < 8; nf++) o[nf][r] *= fac;
        mrow[r] = mnew;
      }
    }
    float p0[4], p1[4];
#pragma unroll
    for (int r = 0; r < 4; r++) {
      p0[r] = __expf(s0[r] - mrow[r]);          // bounded by e^8
      p1[r] = __expf(s1[r] - mrow[r]);
      lsum[r] += p0[r] + p1[r];
    }
    // ---- P -> LDS (stride 40 = 80B rows; wave-private) ----
#pragma unroll
    for (int r = 0; r < 4; r++) {
      Plds[w][(lg * 4 + r) * 40 + l15]      = f2bf(p0[r]);
      Plds[w][(lg * 4 + r) * 40 + 16 + l15] = f2bf(p1[r]);
    }
    bf16x8 pf = *(const bf16x8*)&Plds[w][l15 * 40 + lg * 8];
    // ---- PV ----
    __builtin_amdgcn_s_setprio(1);
#pragma unroll
    for (int nf = 0; nf < 8; nf++)
      o[nf] = __builtin_amdgcn_mfma_f32_16x16x32_bf16(pf, vf[nf], o[nf], 0, 0, 0);
    __builtin_amdgcn_s_setprio(0);
  }

  // epilogue: reduce row sums across the 16 lanes, divide, write bf16
  float inv[4];
#pragma unroll
  for (int r = 0; r < 4; r++) {
    float s = lsum[r];
    s += __shfl_xor(s, 1);
    s += __shfl_xor(s, 2);
    s += __shfl_xor(s, 4);
    s += __shfl_xor(s, 8);
    inv[r] = 1.f / s;
  }
  u16* ob = O + (size_t)(b * SQ_ + q0 + lg * 4) * E_ + h * D_ + l15;
#pragma unroll
  for (int r = 0; r < 4; r++) {
#pragma unroll
    for (int nf = 0; nf < 8; nf++)
      ob[(size_t)r * E_ + nf * 16] = f2bf(o[nf][r] * inv[r]);
  }
}

// ---------------- LayerNorm over E=2048, bf16 in -> bf16 out ----------------
__global__ __launch_bounds__(256)
void ln_kernel(const u16* __restrict__ X, const float* __restrict__ gam,
               const float* __restrict__ bet, u16* __restrict__ Y)
{
  __shared__ float red[8];
  const int row = blockIdx.x, t = threadIdx.x;
  const u16* x = X + (size_t)row * E_ + t * 8;
  uint4 raw = *(const uint4*)x;
  float v[8];
  v[0] = bf2f((u16)(raw.x & 0xffff)); v[1] = bf2f((u16)(raw.x >> 16));
  v[2] = bf2f((u16)(raw.y & 0xffff)); v[3] = bf2f((u16)(raw.y >> 16));
  v[4] = bf2f((u16)(raw.z & 0xffff)); v[5] = bf2f((u16)(raw.z >> 16));
  v[6] = bf2f((u16)(raw.w & 0xffff)); v[7] = bf2f((u16)(raw.w >> 16));
  float s = 0.f, ss = 0.f;
#pragma unroll
  for (int i = 0; i < 8; i++) { s += v[i]; ss += v[i] * v[i]; }
#pragma unroll
  for (int off = 1; off < 64; off <<= 1) { s += __shfl_xor(s, off); ss += __shfl_xor(ss, off); }
  const int wv = t >> 6, lane = t & 63;
  if (lane == 0) { red[wv] = s; red[4 + wv] = ss; }
  __syncthreads();
  s  = red[0] + red[1] + red[2] + red[3];
  ss = red[4] + red[5] + red[6] + red[7];
  const float mean = s * (1.f / E_);
  const float var  = ss * (1.f / E_) - mean * mean;
  const float rstd = rsqrtf(var + 1e-5f);
  const float4* gp = (const float4*)(gam + t * 8);
  const float4* bp = (const float4*)(bet + t * 8);
  float4 g0 = gp[0], g1 = gp[1], b0 = bp[0], b1 = bp[1];
  float y[8];
  y[0] = (v[0] - mean) * rstd * g0.x + b0.x;
  y[1] = (v[1] - mean) * rstd * g0.y + b0.y;
  y[2] = (v[2] - mean) * rstd * g0.z + b0.z;
  y[3] = (v[3] - mean) * rstd * g0.w + b0.w;
  y[4] = (v[4] - mean) * rstd * g1.x + b1.x;
  y[5] = (v[5] - mean) * rstd * g1.y + b1.y;
  y[6] = (v[6] - mean) * rstd * g1.z + b1.z;
  y[7] = (v[7] - mean) * rstd * g1.w + b1.w;
  uint4 o;
  o.x = pack2(y[0], y[1]); o.y = pack2(y[2], y[3]);
  o.z = pack2(y[4], y[5]); o.w = pack2(y[6], y[7]);
  *(uint4*)(Y + (size_t)row * E_ + t * 8) = o;
}

extern "C" void kernel_launch(void* const* d_in, const int* in_sizes, int n_in,
                              void* d_out, int out_size, void* d_ws, size_t ws_size,
                              hipStream_t stream) {
  const float* query = (const float*)d_in[0];
  const float* key_  = (const float*)d_in[1];
  const float* value = (const float*)d_in[2];
  const float* Wq = (const float*)d_in[3];
  const float* bq = (const float*)d_in[4];
  const float* Wk = (const float*)d_in[5];
  const float* bk = (const float*)d_in[6];
  const float* Wv = (const float*)d_in[7];
  const float* bv = (const float*)d_in[8];
  const float* ln_g = (const float*)d_in[9];
  const float* ln_b = (const float*)d_in[10];
  const float* Wo = (const float*)d_in[11];
  const float* bo = (const float*)d_in[12];
  float* out = (float*)d_out;

  char* ws = (char*)d_ws;
  u16* wqb = (u16*)(ws + 0);            // 8 MB each
  u16* wkb = (u16*)(ws + 8388608);
  u16* wvb = (u16*)(ws + 16777216);
  u16* wob = (u16*)(ws + 25165824);
  u16* xb  = (u16*)(ws + 33554432);     // 32 MB, reused: cast buf -> attn out
  u16* qp  = (u16*)(ws + 67108864);     // 32 MB, reused: Q proj -> LN out
  u16* kp  = (u16*)(ws + 100663296);    // 32 MB
  u16* vt  = (u16*)(ws + 134217728);    // 32 MB  (total 160 MB)
  u16* attn  = xb;
  u16* lnout = qp;

  const dim3 blk(256);
  const dim3 ggrid(E_ / 128, (B_ * SQ_) / 128);  // (16, 64)
  const float qscale = 0.08838834764831845f;      // 1/sqrt(128)

  // weight casts
  cast_kernel<<<EE_ / 8 / 256, blk, 0, stream>>>(Wq, wqb, EE_ / 8);
  cast_kernel<<<EE_ / 8 / 256, blk, 0, stream>>>(Wk, wkb, EE_ / 8);
  cast_kernel<<<EE_ / 8 / 256, blk, 0, stream>>>(Wv, wvb, EE_ / 8);
  cast_kernel<<<EE_ / 8 / 256, blk, 0, stream>>>(Wo, wob, EE_ / 8);

  // Q = (query @ Wq^T + bq) * 1/sqrt(D)
  cast_kernel<<<BSE_ / 8 / 256, blk, 0, stream>>>(query, xb, BSE_ / 8);
  gemm_bt<0><<<ggrid, blk, 0, stream>>>(xb, wqb, bq, qp, B_ * SQ_, E_, E_, qscale);
  // K
  cast_kernel<<<BSE_ / 8 / 256, blk, 0, stream>>>(key_, xb, BSE_ / 8);
  gemm_bt<0><<<ggrid, blk, 0, stream>>>(xb, wkb, bk, kp, B_ * SQ_, E_, E_, 1.0f);
  // V (transposed per-head write)
  cast_kernel<<<BSE_ / 8 / 256, blk, 0, stream>>>(value, xb, BSE_ / 8);
  gemm_bt<1><<<ggrid, blk, 0, stream>>>(xb, wvb, bv, vt, B_ * SQ_, E_, E_, 1.0f);

  // attention
  attn_fwd<<<dim3(SQ_ / 64, B_ * H_), blk, 0, stream>>>(qp, kp, vt, attn);

  // layernorm
  ln_kernel<<<B_ * SQ_, blk, 0, stream>>>(attn, ln_g, ln_b, lnout);

  // out = lnout @ Wo^T + bo  (f32 out)
  gemm_bt<2><<<ggrid, blk, 0, stream>>>(lnout, wob, bo, out, B_ * SQ_, E_, E_, 1.0f);
}

// Round 5
// 1024.252 us; speedup vs baseline: 1.5826x; 1.5812x over previous
//
#include <hip/hip_runtime.h>

// Problem constants (B, SQ, SKV, E, H, D) = (4, 2048, 2048, 2048, 16, 128)
#define B_   4
#define SQ_  2048
#define SKV_ 2048
#define E_   2048
#define H_   16
#define D_   128
#define EE_  (E_*E_)        // 4194304
#define BSE_ (B_*SQ_*E_)    // 16777216

typedef unsigned short u16;
typedef unsigned int   u32;
typedef __attribute__((ext_vector_type(4))) float f32x4;
typedef __attribute__((ext_vector_type(8))) short bf16x8;

__device__ __forceinline__ u16 f2bf(float f) {
  union { float f; u32 u; } x; x.f = f;
  u32 r = x.u + 0x7FFFu + ((x.u >> 16) & 1u);   // round-to-nearest-even
  return (u16)(r >> 16);
}
__device__ __forceinline__ float bf2f(u16 h) {
  union { u32 u; float f; } x; x.u = ((u32)h) << 16; return x.f;
}
__device__ __forceinline__ u32 pack2(float a, float b) {
  return (u32)f2bf(a) | ((u32)f2bf(b) << 16);
}
__device__ __forceinline__ void gload_lds16(const void* g, void* l) {
  __builtin_amdgcn_global_load_lds(
      (const __attribute__((address_space(1))) u32*)g,
      (__attribute__((address_space(3))) u32*)l, 16, 0, 0);
}

// ---------------- f32 -> bf16 cast (8 elems/thread) ----------------
__global__ __launch_bounds__(256)
void cast_kernel(const float* __restrict__ in, u16* __restrict__ out, int n8) {
  int i = blockIdx.x * 256 + threadIdx.x;
  if (i >= n8) return;
  const float4* p = (const float4*)(in + (size_t)i * 8);
  float4 a = p[0], b = p[1];
  uint4 o;
  o.x = pack2(a.x, a.y); o.y = pack2(a.z, a.w);
  o.z = pack2(b.x, b.y); o.w = pack2(b.z, b.w);
  *(uint4*)(out + (size_t)i * 8) = o;
}

// ---------------- m97-style bf16 GEMM: C = (A @ Bt^T + bias) * alpha ----------
// A: MxK row-major bf16.  Bt: NxK row-major bf16 (i.e. torch Linear weight).
// OMODE 0: bf16 out [M][N].  OMODE 1: bf16 out transposed per-batch
//   (Vt[b][n][s]).  OMODE 2: f32 out [M][N].
// OMODE 3: bf16 out per-head Kh[b][h][s][d], n = h*128+d, m = b*2048+s.
template<int OMODE>
__global__ __launch_bounds__(256)
void gemm_bt(const u16* __restrict__ A, const u16* __restrict__ Bt,
             const float* __restrict__ bias, void* __restrict__ Cout,
             int M, int N, int K, float alpha)
{
  __shared__ __align__(16) u16 As[128 * 32];
  __shared__ __align__(16) u16 Bs[128 * 32];
  const int tid  = threadIdx.x;
  const int lane = tid & 63;
  const int l15  = lane & 15, lg = lane >> 4;
  const int w = tid >> 6, wr = w >> 1, wc = w & 1;
  const int m0 = blockIdx.y * 128, n0 = blockIdx.x * 128;

  const int c0 = tid, c1 = tid + 256;
  const u16* ga0 = A  + (size_t)(m0 + (c0 >> 2)) * K + (c0 & 3) * 8;
  const u16* ga1 = A  + (size_t)(m0 + (c1 >> 2)) * K + (c1 & 3) * 8;
  const u16* gb0 = Bt + (size_t)(n0 + (c0 >> 2)) * K + (c0 & 3) * 8;
  const u16* gb1 = Bt + (size_t)(n0 + (c1 >> 2)) * K + (c1 & 3) * 8;
  u16* la0 = &As[c0 * 8]; u16* la1 = &As[c1 * 8];
  u16* lb0 = &Bs[c0 * 8]; u16* lb1 = &Bs[c1 * 8];

  f32x4 acc[4][4];
#pragma unroll
  for (int i = 0; i < 4; i++)
#pragma unroll
    for (int j = 0; j < 4; j++) acc[i][j] = (f32x4){0.f, 0.f, 0.f, 0.f};

  const u16* pa = &As[(wr * 64 + l15) * 32 + lg * 8];
  const u16* pb = &Bs[(wc * 64 + l15) * 32 + lg * 8];

  for (int kt = 0; kt < K; kt += 32) {
    gload_lds16(ga0 + kt, la0);
    gload_lds16(ga1 + kt, la1);
    gload_lds16(gb0 + kt, lb0);
    gload_lds16(gb1 + kt, lb1);
    __syncthreads();
    bf16x8 af[4], bfr[4];
#pragma unroll
    for (int i = 0; i < 4; i++) {
      af[i]  = *(const bf16x8*)(pa + i * 16 * 32);
      bfr[i] = *(const bf16x8*)(pb + i * 16 * 32);
    }
#pragma unroll
    for (int mi = 0; mi < 4; mi++)
#pragma unroll
      for (int ni = 0; ni < 4; ni++)
        acc[mi][ni] = __builtin_amdgcn_mfma_f32_16x16x32_bf16(af[mi], bfr[ni], acc[mi][ni], 0, 0, 0);
    __syncthreads();
  }

  // Epilogue. C/D layout: col = lane&15, row = (lane>>4)*4 + reg.
#pragma unroll
  for (int ni = 0; ni < 4; ni++) {
    const int n = n0 + wc * 64 + ni * 16 + l15;
    const float bs = bias[n];
#pragma unroll
    for (int mi = 0; mi < 4; mi++) {
      const int mbase = m0 + wr * 64 + mi * 16 + lg * 4;
      f32x4 v = acc[mi][ni];
      if constexpr (OMODE == 2) {
        float* C = (float*)Cout;
#pragma unroll
        for (int r = 0; r < 4; r++) C[(size_t)(mbase + r) * N + n] = (v[r] + bs) * alpha;
      } else if constexpr (OMODE == 0) {
        u16* C = (u16*)Cout;
#pragma unroll
        for (int r = 0; r < 4; r++) C[(size_t)(mbase + r) * N + n] = f2bf((v[r] + bs) * alpha);
      } else if constexpr (OMODE == 3) {
        u16* C = (u16*)Cout;
        const int b = mbase >> 11;           // /2048 (block rows stay in one b)
        const int s = mbase & 2047;
        u16* p = C + ((size_t)(b * H_ + (n >> 7)) * SKV_ + s) * D_ + (n & 127);
#pragma unroll
        for (int r = 0; r < 4; r++) p[(size_t)r * D_] = f2bf((v[r] + bs) * alpha);
      } else {
        u16* C = (u16*)Cout;
        const int b = mbase / SKV_, s = mbase & (SKV_ - 1);  // 4 rows stay in one b
        ushort4 o;
        o.x = f2bf((v[0] + bs) * alpha); o.y = f2bf((v[1] + bs) * alpha);
        o.z = f2bf((v[2] + bs) * alpha); o.w = f2bf((v[3] + bs) * alpha);
        *(ushort4*)((u16*)C + (size_t)b * N * SKV_ + (size_t)n * SKV_ + s) = o;
      }
    }
  }
}

// ---------------- flash attention (LDS-staged, double-buffered) ----------------
// Qp: [B,SQ,E] bf16 (pre-scaled by 1/sqrt(D)), Kh: [B,H,SKV,D] bf16,
// Vt: [B][h*D+d][s] bf16, O: [B,SQ,E] bf16.
// Block = 4 waves x 16 q-rows, KV tile = 32.
// K tile LDS [32 s][128 d] rows 256B, chunk swizzle j^(s&7).
// V tile LDS [128 d][32 s] rows 64B, chunk swizzle c^((d>>1)&3).
// Staging: linear LDS dest (global_load_lds), inverse-swizzled global source,
// swizzled ds_read (rule #21). One __syncthreads per tile (T3-lite).
// XCD-chunked 1-D grid so one head's 32 q-blocks share an XCD's L2.
__global__ __launch_bounds__(256)
void attn_fwd(const u16* __restrict__ Qp, const u16* __restrict__ Kh,
              const u16* __restrict__ Vt, u16* __restrict__ O)
{
  __shared__ __align__(16) u16 Ks[2][32 * 128];
  __shared__ __align__(16) u16 Vs[2][128 * 32];
  __shared__ __align__(16) u16 Plds[4][16 * 40];

  const int tid  = threadIdx.x;
  const int lane = tid & 63;
  const int w    = tid >> 6;
  const int l15  = lane & 15, lg = lane >> 4;

  // XCD-chunked remap: 2048 blocks, xcd = wg&7 (round-robin dispatch),
  // logical = xcd*256 + slot -> consecutive logical ids stay on one XCD.
  const int wg = blockIdx.x;
  const int logical = (wg & 7) * 256 + (wg >> 3);
  const int bh = logical >> 5, qb = logical & 31;
  const int b = bh >> 4, h = bh & 15;
  const int q0 = qb * 64 + w * 16;

  // Q fragments: 4 x (16 rows x 32 d)
  bf16x8 qf[4];
  {
    const u16* qp = Qp + (size_t)(b * SQ_ + q0 + l15) * E_ + h * D_ + lg * 8;
#pragma unroll
    for (int kk = 0; kk < 4; kk++) qf[kk] = *(const bf16x8*)(qp + kk * 32);
  }

  f32x4 o[8];
#pragma unroll
  for (int i = 0; i < 8; i++) o[i] = (f32x4){0.f, 0.f, 0.f, 0.f};
  float mrow[4] = {-3e38f, -3e38f, -3e38f, -3e38f};   // wave-uniform per row
  float lsum[4] = {0.f, 0.f, 0.f, 0.f};               // per-lane partials

  const u16* khead = Kh + (size_t)(b * H_ + h) * SKV_ * D_;
  const u16* vhead = Vt + (size_t)b * E_ * SKV_ + (size_t)h * D_ * SKV_;

  // staging: 512 x 16B chunks per 8KB tile; thread covers c = tid, tid+256.
  const int ck0 = tid, ck1 = tid + 256;
  const int ks0 = ck0 >> 4, kc0 = (ck0 & 15) ^ (ks0 & 7);
  const int ks1 = ck1 >> 4, kc1 = (ck1 & 15) ^ (ks1 & 7);
  const int vd0 = ck0 >> 2, vc0 = (ck0 & 3) ^ ((vd0 >> 1) & 3);
  const int vd1 = ck1 >> 2, vc1 = (ck1 & 3) ^ ((vd1 >> 1) & 3);

#define STAGE_KV(buf, kv0)                                                     \
  do {                                                                         \
    gload_lds16(khead + (size_t)((kv0) + ks0) * D_ + kc0 * 8, &Ks[buf][ck0 * 8]); \
    gload_lds16(khead + (size_t)((kv0) + ks1) * D_ + kc1 * 8, &Ks[buf][ck1 * 8]); \
    gload_lds16(vhead + (size_t)vd0 * SKV_ + (kv0) + vc0 * 8, &Vs[buf][ck0 * 8]); \
    gload_lds16(vhead + (size_t)vd1 * SKV_ + (kv0) + vc1 * 8, &Vs[buf][ck1 * 8]); \
  } while (0)

  STAGE_KV(0, 0);
  __syncthreads();

  int cur = 0;
  for (int t = 0; t < SKV_ / 32; ++t) {
    if (t < SKV_ / 32 - 1) STAGE_KV(cur ^ 1, (t + 1) * 32);

    // ---- K fragments from LDS (swizzled) ----
    bf16x8 kfr[8];
#pragma unroll
    for (int kk = 0; kk < 4; kk++) {
      const int sA = l15, sB = 16 + l15;
      kfr[kk]     = *(const bf16x8*)&Ks[cur][sA * 128 + (((kk * 4 + lg) ^ (sA & 7)) * 8)];
      kfr[4 + kk] = *(const bf16x8*)&Ks[cur][sB * 128 + (((kk * 4 + lg) ^ (sB & 7)) * 8)];
    }
    // ---- QK^T ----
    f32x4 s0 = (f32x4){0.f,0.f,0.f,0.f}, s1 = (f32x4){0.f,0.f,0.f,0.f};
    __builtin_amdgcn_s_setprio(1);
#pragma unroll
    for (int kk = 0; kk < 4; kk++) {
      s0 = __builtin_amdgcn_mfma_f32_16x16x32_bf16(qf[kk], kfr[kk],     s0, 0, 0, 0);
      s1 = __builtin_amdgcn_mfma_f32_16x16x32_bf16(qf[kk], kfr[4 + kk], s1, 0, 0, 0);
    }
    __builtin_amdgcn_s_setprio(0);

    // ---- online softmax, defer-max ----
    float lmax[4];
#pragma unroll
    for (int r = 0; r < 4; r++) lmax[r] = fmaxf(s0[r], s1[r]);
    int c = (lmax[0] <= mrow[0] + 8.f) & (lmax[1] <= mrow[1] + 8.f) &
            (lmax[2] <= mrow[2] + 8.f) & (lmax[3] <= mrow[3] + 8.f);
    if (!__all(c)) {
#pragma unroll
      for (int r = 0; r < 4; r++) {
        float mx = lmax[r];
        mx = fmaxf(mx, __shfl_xor(mx, 1));
        mx = fmaxf(mx, __shfl_xor(mx, 2));
        mx = fmaxf(mx, __shfl_xor(mx, 4));
        mx = fmaxf(mx, __shfl_xor(mx, 8));
        const float mnew = fmaxf(mrow[r], mx);
        const float fac = __expf(mrow[r] - mnew);
        lsum[r] *= fac;
#pragma unroll
        for (int nf = 0; nf < 8; nf++) o[nf][r] *= fac;
        mrow[r] = mnew;
      }
    }
    float p0[4], p1[4];
#pragma unroll
    for (int r = 0; r < 4; r++) {
      p0[r] = __expf(s0[r] - mrow[r]);          // bounded by e^8
      p1[r] = __expf(s1[r] - mrow[r]);
      lsum[r] += p0[r] + p1[r];
    }
    // ---- P -> LDS (stride 40; wave-private) ----
#pragma unroll
    for (int r = 0; r < 4; r++) {
      Plds[w][(lg * 4 + r) * 40 + l15]      = f2bf(p0[r]);
      Plds[w][(lg * 4 + r) * 40 + 16 + l15] = f2bf(p1[r]);
    }
    bf16x8 pf = *(const bf16x8*)&Plds[w][l15 * 40 + lg * 8];

    // ---- V fragments from LDS (swizzled) + PV ----
    bf16x8 vfr[8];
#pragma unroll
    for (int nf = 0; nf < 8; nf++) {
      const int d = nf * 16 + l15;
      vfr[nf] = *(const bf16x8*)&Vs[cur][d * 32 + ((lg ^ ((d >> 1) & 3)) * 8)];
    }
    __builtin_amdgcn_s_setprio(1);
#pragma unroll
    for (int nf = 0; nf < 8; nf++)
      o[nf] = __builtin_amdgcn_mfma_f32_16x16x32_bf16(pf, vfr[nf], o[nf], 0, 0, 0);
    __builtin_amdgcn_s_setprio(0);

    __syncthreads();   // staged next tile ready; all reads of cur done
    cur ^= 1;
  }
#undef STAGE_KV

  // epilogue: reduce row sums across the 16 lanes, divide, write bf16
  float inv[4];
#pragma unroll
  for (int r = 0; r < 4; r++) {
    float s = lsum[r];
    s += __shfl_xor(s, 1);
    s += __shfl_xor(s, 2);
    s += __shfl_xor(s, 4);
    s += __shfl_xor(s, 8);
    inv[r] = 1.f / s;
  }
  u16* ob = O + (size_t)(b * SQ_ + q0 + lg * 4) * E_ + h * D_ + l15;
#pragma unroll
  for (int r = 0; r < 4; r++) {
#pragma unroll
    for (int nf = 0; nf < 8; nf++)
      ob[(size_t)r * E_ + nf * 16] = f2bf(o[nf][r] * inv[r]);
  }
}

// ---------------- LayerNorm over E=2048, bf16 in -> bf16 out ----------------
__global__ __launch_bounds__(256)
void ln_kernel(const u16* __restrict__ X, const float* __restrict__ gam,
               const float* __restrict__ bet, u16* __restrict__ Y)
{
  __shared__ float red[8];
  const int row = blockIdx.x, t = threadIdx.x;
  const u16* x = X + (size_t)row * E_ + t * 8;
  uint4 raw = *(const uint4*)x;
  float v[8];
  v[0] = bf2f((u16)(raw.x & 0xffff)); v[1] = bf2f((u16)(raw.x >> 16));
  v[2] = bf2f((u16)(raw.y & 0xffff)); v[3] = bf2f((u16)(raw.y >> 16));
  v[4] = bf2f((u16)(raw.z & 0xffff)); v[5] = bf2f((u16)(raw.z >> 16));
  v[6] = bf2f((u16)(raw.w & 0xffff)); v[7] = bf2f((u16)(raw.w >> 16));
  float s = 0.f, ss = 0.f;
#pragma unroll
  for (int i = 0; i < 8; i++) { s += v[i]; ss += v[i] * v[i]; }
#pragma unroll
  for (int off = 1; off < 64; off <<= 1) { s += __shfl_xor(s, off); ss += __shfl_xor(ss, off); }
  const int wv = t >> 6, lane = t & 63;
  if (lane == 0) { red[wv] = s; red[4 + wv] = ss; }
  __syncthreads();
  s  = red[0] + red[1] + red[2] + red[3];
  ss = red[4] + red[5] + red[6] + red[7];
  const float mean = s * (1.f / E_);
  const float var  = ss * (1.f / E_) - mean * mean;
  const float rstd = rsqrtf(var + 1e-5f);
  const float4* gp = (const float4*)(gam + t * 8);
  const float4* bp = (const float4*)(bet + t * 8);
  float4 g0 = gp[0], g1 = gp[1], b0 = bp[0], b1 = bp[1];
  float y[8];
  y[0] = (v[0] - mean) * rstd * g0.x + b0.x;
  y[1] = (v[1] - mean) * rstd * g0.y + b0.y;
  y[2] = (v[2] - mean) * rstd * g0.z + b0.z;
  y[3] = (v[3] - mean) * rstd * g0.w + b0.w;
  y[4] = (v[4] - mean) * rstd * g1.x + b1.x;
  y[5] = (v[5] - mean) * rstd * g1.y + b1.y;
  y[6] = (v[6] - mean) * rstd * g1.z + b1.z;
  y[7] = (v[7] - mean) * rstd * g1.w + b1.w;
  uint4 o;
  o.x = pack2(y[0], y[1]); o.y = pack2(y[2], y[3]);
  o.z = pack2(y[4], y[5]); o.w = pack2(y[6], y[7]);
  *(uint4*)(Y + (size_t)row * E_ + t * 8) = o;
}

extern "C" void kernel_launch(void* const* d_in, const int* in_sizes, int n_in,
                              void* d_out, int out_size, void* d_ws, size_t ws_size,
                              hipStream_t stream) {
  const float* query = (const float*)d_in[0];
  const float* key_  = (const float*)d_in[1];
  const float* value = (const float*)d_in[2];
  const float* Wq = (const float*)d_in[3];
  const float* bq = (const float*)d_in[4];
  const float* Wk = (const float*)d_in[5];
  const float* bk = (const float*)d_in[6];
  const float* Wv = (const float*)d_in[7];
  const float* bv = (const float*)d_in[8];
  const float* ln_g = (const float*)d_in[9];
  const float* ln_b = (const float*)d_in[10];
  const float* Wo = (const float*)d_in[11];
  const float* bo = (const float*)d_in[12];
  float* out = (float*)d_out;

  char* ws = (char*)d_ws;
  u16* wqb = (u16*)(ws + 0);            // 8 MB each
  u16* wkb = (u16*)(ws + 8388608);
  u16* wvb = (u16*)(ws + 16777216);
  u16* wob = (u16*)(ws + 25165824);
  u16* xb  = (u16*)(ws + 33554432);     // 32 MB, reused: cast buf -> attn out
  u16* qp  = (u16*)(ws + 67108864);     // 32 MB, reused: Q proj -> LN out
  u16* kp  = (u16*)(ws + 100663296);    // 32 MB (Kh per-head layout)
  u16* vt  = (u16*)(ws + 134217728);    // 32 MB  (total 160 MB)
  u16* attn  = xb;
  u16* lnout = qp;

  const dim3 blk(256);
  const dim3 ggrid(E_ / 128, (B_ * SQ_) / 128);  // (16, 64)
  const float qscale = 0.08838834764831845f;      // 1/sqrt(128)

  // weight casts
  cast_kernel<<<EE_ / 8 / 256, blk, 0, stream>>>(Wq, wqb, EE_ / 8);
  cast_kernel<<<EE_ / 8 / 256, blk, 0, stream>>>(Wk, wkb, EE_ / 8);
  cast_kernel<<<EE_ / 8 / 256, blk, 0, stream>>>(Wv, wvb, EE_ / 8);
  cast_kernel<<<EE_ / 8 / 256, blk, 0, stream>>>(Wo, wob, EE_ / 8);

  // Q = (query @ Wq^T + bq) * 1/sqrt(D)
  cast_kernel<<<BSE_ / 8 / 256, blk, 0, stream>>>(query, xb, BSE_ / 8);
  gemm_bt<0><<<ggrid, blk, 0, stream>>>(xb, wqb, bq, qp, B_ * SQ_, E_, E_, qscale);
  // K (per-head layout Kh[b][h][s][d])
  cast_kernel<<<BSE_ / 8 / 256, blk, 0, stream>>>(key_, xb, BSE_ / 8);
  gemm_bt<3><<<ggrid, blk, 0, stream>>>(xb, wkb, bk, kp, B_ * SQ_, E_, E_, 1.0f);
  // V (transposed per-head write)
  cast_kernel<<<BSE_ / 8 / 256, blk, 0, stream>>>(value, xb, BSE_ / 8);
  gemm_bt<1><<<ggrid, blk, 0, stream>>>(xb, wvb, bv, vt, B_ * SQ_, E_, E_, 1.0f);

  // attention (1-D grid, XCD-chunked in-kernel)
  attn_fwd<<<dim3((SQ_ / 64) * B_ * H_), blk, 0, stream>>>(qp, kp, vt, attn);

  // layernorm
  ln_kernel<<<B_ * SQ_, blk, 0, stream>>>(attn, ln_g, ln_b, lnout);

  // out = lnout @ Wo^T + bo  (f32 out)
  gemm_bt<2><<<ggrid, blk, 0, stream>>>(lnout, wob, bo, out, B_ * SQ_, E_, E_, 1.0f);
}